// Round 1
// baseline (788.370 us; speedup 1.0000x reference)
//
#include <hip/hip_runtime.h>
#include <cmath>

// Problem constants: x [8, 512, 32, 32] fp32
constexpr int Bsz = 8, Cch = 512, NPIX = 1024;   // NPIX = 32*32
constexpr int NG = 32, CPG = Cch / NG;           // 32 groups x 16 ch

// ---------------- reductions ----------------
__device__ inline float wave_reduce_sum(float v) {
#pragma unroll
  for (int off = 32; off > 0; off >>= 1) v += __shfl_xor(v, off, 64);
  return v;
}
__device__ inline float wave_reduce_max(float v) {
#pragma unroll
  for (int off = 32; off > 0; off >>= 1) v = fmaxf(v, __shfl_xor(v, off, 64));
  return v;
}

// ---------------- GroupNorm ----------------
// grid: B*NG blocks (256), 256 threads. Each block: one (batch, group) =
// 16 ch x 1024 px = 16384 floats. Two-pass (L2-resident on 2nd read).
__global__ __launch_bounds__(256) void gn_kernel(
    const float* __restrict__ x, const float* __restrict__ w,
    const float* __restrict__ bb, float* __restrict__ xn) {
  __shared__ float sm[4];
  const int bg = blockIdx.x, b = bg >> 5, g = bg & 31;
  const float* xp = x + ((size_t)(b * Cch + g * CPG)) * NPIX;
  float* op = xn + ((size_t)(b * Cch + g * CPG)) * NPIX;
  float s = 0.f, ss = 0.f;
  for (int i = threadIdx.x * 4; i < CPG * NPIX; i += 256 * 4) {
    float4 v = *(const float4*)(xp + i);
    s += v.x + v.y + v.z + v.w;
    ss += v.x * v.x + v.y * v.y + v.z * v.z + v.w * v.w;
  }
  // block reduce sum (4 waves)
  s = wave_reduce_sum(s);
  if ((threadIdx.x & 63) == 0) sm[threadIdx.x >> 6] = s;
  __syncthreads();
  const float tsum = sm[0] + sm[1] + sm[2] + sm[3];
  __syncthreads();
  ss = wave_reduce_sum(ss);
  if ((threadIdx.x & 63) == 0) sm[threadIdx.x >> 6] = ss;
  __syncthreads();
  const float tsq = sm[0] + sm[1] + sm[2] + sm[3];

  const float inv_n = 1.0f / (CPG * NPIX);
  const float mean = tsum * inv_n;
  const float var = tsq * inv_n - mean * mean;
  const float rstd = rsqrtf(var + 1e-5f);

  for (int i = threadIdx.x * 4; i < CPG * NPIX; i += 256 * 4) {
    const int c = g * CPG + (i >> 10);
    const float wc = w[c] * rstd, bc = bb[c];
    float4 v = *(const float4*)(xp + i);
    float4 o;
    o.x = (v.x - mean) * wc + bc;
    o.y = (v.y - mean) * wc + bc;
    o.z = (v.z - mean) * wc + bc;
    o.w = (v.w - mean) * wc + bc;
    *(float4*)(op + i) = o;
  }
}

// ---------------- tiled fp32 GEMM ----------------
// C[m][n] = alpha * sum_k A(m,k)*B(k,n) + bias[m] + resid[m][n]
// A(m,k) = AT ? A[k*lda+m] : A[m*lda+k]
// B(k,n) = BT ? B[n*ldb+k] : B[k*ldb+n]
// 64x64 block tile, BK=16, 256 threads, 4x4 micro-tile per thread.
template <bool AT, bool BT>
__global__ __launch_bounds__(256) void gemm_kernel(
    const float* __restrict__ A, const float* __restrict__ Bm,
    float* __restrict__ Cm, int K, int lda, int ldb, int ldc,
    long sA, long sB, long sC,
    const float* __restrict__ bias, const float* __restrict__ resid, long sR,
    float alpha) {
  __shared__ float As[16][64];
  __shared__ float Bs[16][64];
  const int t = threadIdx.x;
  const int tx = t & 15, ty = t >> 4;
  const int n0 = blockIdx.x * 64, m0 = blockIdx.y * 64;
  const int bz = blockIdx.z;
  A += sA * bz;
  Bm += sB * bz;
  Cm += sC * bz;

  float acc[4][4] = {};
  for (int k0 = 0; k0 < K; k0 += 16) {
#pragma unroll
    for (int i = t; i < 1024; i += 256) {
      if (AT) {
        const int m = i & 63, kk = i >> 6;
        As[kk][m] = A[(size_t)(k0 + kk) * lda + m0 + m];
      } else {
        const int kk = i & 15, m = i >> 4;
        As[kk][m] = A[(size_t)(m0 + m) * lda + k0 + kk];
      }
    }
#pragma unroll
    for (int i = t; i < 1024; i += 256) {
      if (BT) {
        const int kk = i & 15, n = i >> 4;
        Bs[kk][n] = Bm[(size_t)(n0 + n) * ldb + k0 + kk];
      } else {
        const int n = i & 63, kk = i >> 6;
        Bs[kk][n] = Bm[(size_t)(k0 + kk) * ldb + n0 + n];
      }
    }
    __syncthreads();
#pragma unroll
    for (int kk = 0; kk < 16; ++kk) {
      float av[4], bv[4];
#pragma unroll
      for (int im = 0; im < 4; ++im) av[im] = As[kk][ty * 4 + im];
#pragma unroll
      for (int in = 0; in < 4; ++in) bv[in] = Bs[kk][tx * 4 + in];
#pragma unroll
      for (int im = 0; im < 4; ++im)
#pragma unroll
        for (int in = 0; in < 4; ++in) acc[im][in] += av[im] * bv[in];
    }
    __syncthreads();
  }
#pragma unroll
  for (int im = 0; im < 4; ++im) {
    const int m = m0 + ty * 4 + im;
    const float add = bias ? bias[m] : 0.0f;
    float4 o;
    o.x = acc[im][0] * alpha + add;
    o.y = acc[im][1] * alpha + add;
    o.z = acc[im][2] * alpha + add;
    o.w = acc[im][3] * alpha + add;
    if (resid) {
      const float4 r =
          *(const float4*)(resid + sR * bz + (size_t)m * ldc + n0 + tx * 4);
      o.x += r.x; o.y += r.y; o.z += r.z; o.w += r.w;
    }
    *(float4*)(Cm + (size_t)m * ldc + n0 + tx * 4) = o;
  }
}

// ---------------- row softmax over 1024 ----------------
// grid: B*1024 rows, 256 threads; 1 float4 per thread.
__global__ __launch_bounds__(256) void softmax_kernel(float* __restrict__ attn) {
  __shared__ float sm[4];
  float* p = attn + (size_t)blockIdx.x * 1024;
  const int t = threadIdx.x;
  float4 v = ((float4*)p)[t];
  float m = fmaxf(fmaxf(v.x, v.y), fmaxf(v.z, v.w));
  m = wave_reduce_max(m);
  if ((t & 63) == 0) sm[t >> 6] = m;
  __syncthreads();
  m = fmaxf(fmaxf(sm[0], sm[1]), fmaxf(sm[2], sm[3]));
  v.x = __expf(v.x - m);
  v.y = __expf(v.y - m);
  v.z = __expf(v.z - m);
  v.w = __expf(v.w - m);
  float s = v.x + v.y + v.z + v.w;
  s = wave_reduce_sum(s);
  __syncthreads();
  if ((t & 63) == 0) sm[t >> 6] = s;
  __syncthreads();
  const float inv = 1.0f / (sm[0] + sm[1] + sm[2] + sm[3]);
  v.x *= inv; v.y *= inv; v.z *= inv; v.w *= inv;
  ((float4*)p)[t] = v;
}

// ---------------- launch ----------------
extern "C" void kernel_launch(void* const* d_in, const int* in_sizes, int n_in,
                              void* d_out, int out_size, void* d_ws,
                              size_t ws_size, hipStream_t stream) {
  const float* x = (const float*)d_in[0];
  const float* gnw = (const float*)d_in[1];
  const float* gnb = (const float*)d_in[2];
  const float* qkvw = (const float*)d_in[3];   // [1536, 512]
  const float* qkvb = (const float*)d_in[4];   // [1536]
  const float* projw = (const float*)d_in[5];  // [512, 512]
  const float* projb = (const float*)d_in[6];  // [512]
  float* out = (float*)d_out;

  char* ws = (char*)d_ws;
  float* xn = (float*)ws;                        // 16 MiB [8][512][1024]
  float* qkv = (float*)(ws + (16ull << 20));     // 48 MiB [8][1536][1024]
  float* attn = (float*)(ws + (64ull << 20));    // 32 MiB [8][1024][1024]
  float* obuf = xn;  // xn dead after qkv GEMM -> reuse for attention output

  // 1) GroupNorm
  gn_kernel<<<Bsz * NG, 256, 0, stream>>>(x, gnw, gnb, xn);

  // 2) QKV = qkv_w @ xn + qkv_b   (M=1536, N=1024, K=512)
  gemm_kernel<false, false><<<dim3(16, 24, Bsz), 256, 0, stream>>>(
      qkvw, xn, qkv, 512, 512, 1024, 1024, 0L, 512L * 1024, 1536L * 1024,
      qkvb, nullptr, 0L, 1.0f);

  // 3) S = scale * Q^T K          (M=1024, N=1024, K=512)  [A transposed]
  const float scale = 1.0f / sqrtf(512.0f);
  gemm_kernel<true, false><<<dim3(16, 16, Bsz), 256, 0, stream>>>(
      qkv, qkv + 512 * 1024, attn, 512, 1024, 1024, 1024, 1536L * 1024,
      1536L * 1024, 1024L * 1024, nullptr, nullptr, 0L, scale);

  // 4) row softmax
  softmax_kernel<<<Bsz * 1024, 256, 0, stream>>>(attn);

  // 5) O = V @ P^T                (M=512, N=1024, K=1024)  [B transposed]
  gemm_kernel<false, true><<<dim3(16, 8, Bsz), 256, 0, stream>>>(
      qkv + 1024 * 1024, attn, obuf, 1024, 1024, 1024, 1024, 1536L * 1024,
      1024L * 1024, 512L * 1024, nullptr, nullptr, 0L, 1.0f);

  // 6) out = x + proj_w @ O + proj_b   (M=512, N=1024, K=512)
  gemm_kernel<false, false><<<dim3(16, 8, Bsz), 256, 0, stream>>>(
      projw, obuf, out, 512, 512, 1024, 1024, 0L, 512L * 1024, 512L * 1024,
      projb, x, 512L * 1024, 1.0f);
}

// Round 2
// 215.361 us; speedup vs baseline: 3.6607x; 3.6607x over previous
//
#include <hip/hip_runtime.h>
#include <cmath>

// Problem: x [8, 512, 32, 32] fp32. GroupNorm(32) -> QKV 1x1 -> attention -> proj 1x1 -> +x
constexpr int Bsz = 8, Cch = 512, NPIX = 1024;
constexpr int NG = 32, CPG = 16;

typedef __attribute__((ext_vector_type(4))) float f32x4;
typedef __attribute__((ext_vector_type(8))) short s16x8;

#define GLOBAL_AS __attribute__((address_space(1)))
#define LDS_AS __attribute__((address_space(3)))

__device__ inline short f2bf(float f) {  // RNE fp32 -> bf16
  union { float f; unsigned u; } c = {f};
  unsigned r = (c.u + 0x7fffu + ((c.u >> 16) & 1u)) >> 16;
  return (short)r;
}

__device__ inline float wave_reduce_sum(float v) {
#pragma unroll
  for (int off = 32; off > 0; off >>= 1) v += __shfl_xor(v, off, 64);
  return v;
}
__device__ inline float wave_reduce_max(float v) {
#pragma unroll
  for (int off = 32; off > 0; off >>= 1) v = fmaxf(v, __shfl_xor(v, off, 64));
  return v;
}

// ---------------- fp32 -> bf16 weight conversion ----------------
__global__ __launch_bounds__(256) void cvt_kernel(const float* __restrict__ in,
                                                  short* __restrict__ out, int n) {
  const int i = (blockIdx.x * 256 + threadIdx.x) * 4;
  if (i < n) {
    float4 v = *(const float4*)(in + i);
    short o[4] = {f2bf(v.x), f2bf(v.y), f2bf(v.z), f2bf(v.w)};
    *(uint2*)(out + i) = *(const uint2*)o;
  }
}

// ---------------- GroupNorm, writes TRANSPOSED bf16 xnt[b][pix][c] ----------------
__global__ __launch_bounds__(256) void gn_kernel(
    const float* __restrict__ x, const float* __restrict__ w,
    const float* __restrict__ bb, short* __restrict__ xnt) {
  __shared__ float sm[8];
  const int bg = blockIdx.x, b = bg >> 5, g = bg & 31;
  const float* xp = x + ((size_t)(b * Cch + g * CPG)) * NPIX;
  float s = 0.f, ss = 0.f;
  for (int i = threadIdx.x * 4; i < CPG * NPIX; i += 1024) {
    float4 v = *(const float4*)(xp + i);
    s += v.x + v.y + v.z + v.w;
    ss += v.x * v.x + v.y * v.y + v.z * v.z + v.w * v.w;
  }
  s = wave_reduce_sum(s);
  ss = wave_reduce_sum(ss);
  const int wv = threadIdx.x >> 6;
  if ((threadIdx.x & 63) == 0) { sm[wv] = s; sm[4 + wv] = ss; }
  __syncthreads();
  const float tsum = sm[0] + sm[1] + sm[2] + sm[3];
  const float tsq = sm[4] + sm[5] + sm[6] + sm[7];
  const float inv_n = 1.0f / (CPG * NPIX);
  const float mean = tsum * inv_n;
  const float rstd = rsqrtf(tsq * inv_n - mean * mean + 1e-5f);
  float wc[CPG], bc[CPG];
#pragma unroll
  for (int c = 0; c < CPG; ++c) {
    wc[c] = w[g * CPG + c] * rstd;
    bc[c] = bb[g * CPG + c] - mean * wc[c];
  }
  for (int p = threadIdx.x; p < NPIX; p += 256) {
    short ov[CPG];
#pragma unroll
    for (int c = 0; c < CPG; ++c)
      ov[c] = f2bf(xp[(size_t)c * NPIX + p] * wc[c] + bc[c]);
    short* op = xnt + ((size_t)(b * NPIX + p)) * Cch + g * CPG;
    *(uint4*)op = *(const uint4*)&ov[0];
    *(uint4*)(op + 8) = *(const uint4*)&ov[8];
  }
}

// ---------------- bf16 MFMA GEMM: C[m][n] = sum_k A[m][k]*B[n][k] ----------------
// Both operands row-major with k contiguous ("TN"). 128x128 tile, BK=32,
// 256 threads = 4 waves, each wave 64x64 = 4x4 mfma_f32_16x16x32_bf16.
// LDS is fragment-ordered so global_load_lds staging is linear and
// ds_read_b128 fragment reads are conflict-free.
// EPI 0: qkv split  -> m<1024: bf16 Cq[n*ldc+m] (+bias); else bf16 C2[(m-1024)*ldc+n] (+bias)
// EPI 1: fp32 C[m*ldc+n] = acc*alpha
// EPI 2: bf16 C[m*ldc+n] = acc
// EPI 3: fp32 C[m*ldc+n] = acc + bias[m] + resid[m*ldc+n]
template <int EPI>
__global__ __launch_bounds__(256) void mfma_gemm(
    const short* __restrict__ A, const short* __restrict__ B, int K, int lda,
    int ldb, long sA, long sB, const float* __restrict__ bias, float alpha,
    void* __restrict__ Cp, long sC, int ldc, void* __restrict__ C2p, long sC2,
    const float* __restrict__ resid, long sR) {
  __shared__ __align__(16) short Asl[4096];  // 128 x 32 bf16, fragment-ordered
  __shared__ __align__(16) short Bsl[4096];
  const int t = threadIdx.x;
  const int lane = t & 63, wave = t >> 6;
  const int bz = blockIdx.z;
  const int m0 = blockIdx.y * 128, n0 = blockIdx.x * 128;
  A += sA * bz;
  B += sB * bz;

  // staging descriptors: call i stages 16B chunk s=i*256+t
  // s decodes: mt=s>>6, q=(s>>4)&3, r=s&15 ; row = mt*16+r, k-quad = q
  const short* ga[2];
  const short* gb[2];
  short* la[2];
  short* lb[2];
#pragma unroll
  for (int i = 0; i < 2; ++i) {
    const int s = i * 256 + t;
    const int row = ((s >> 6) * 16) + (s & 15);
    const int q = (s >> 4) & 3;
    ga[i] = A + (size_t)(m0 + row) * lda + q * 8;
    gb[i] = B + (size_t)(n0 + row) * ldb + q * 8;
    la[i] = Asl + s * 8;
    lb[i] = Bsl + s * 8;
  }

  f32x4 acc[4][4] = {};
  const int wm = wave & 1, wn = wave >> 1;

  for (int k0 = 0; k0 < K; k0 += 32) {
#pragma unroll
    for (int i = 0; i < 2; ++i) {
      __builtin_amdgcn_global_load_lds((const GLOBAL_AS void*)ga[i],
                                       (LDS_AS void*)la[i], 16, 0, 0);
      __builtin_amdgcn_global_load_lds((const GLOBAL_AS void*)gb[i],
                                       (LDS_AS void*)lb[i], 16, 0, 0);
      ga[i] += 32;
      gb[i] += 32;
    }
    __syncthreads();
    s16x8 af[4], bf[4];
#pragma unroll
    for (int i = 0; i < 4; ++i) {
      af[i] = *(const s16x8*)(Asl + (wm * 4 + i) * 512 + lane * 8);
      bf[i] = *(const s16x8*)(Bsl + (wn * 4 + i) * 512 + lane * 8);
    }
#pragma unroll
    for (int im = 0; im < 4; ++im)
#pragma unroll
      for (int in = 0; in < 4; ++in)
        acc[im][in] = __builtin_amdgcn_mfma_f32_16x16x32_bf16(
            af[im], bf[in], acc[im][in], 0, 0, 0);
    __syncthreads();
  }

  // epilogue. C/D frag: row m = quad*4+r, col n = lane&15 (within 16x16 tile)
  const int quad = lane >> 4, nn = lane & 15;
#pragma unroll
  for (int im = 0; im < 4; ++im) {
#pragma unroll
    for (int in = 0; in < 4; ++in) {
      const int m = m0 + (wm * 4 + im) * 16 + quad * 4;
      const int n = n0 + (wn * 4 + in) * 16 + nn;
      if (EPI == 0) {
        if (m0 < 1024) {
          short* Cq = (short*)Cp + sC * bz;
          short o[4];
#pragma unroll
          for (int r = 0; r < 4; ++r) o[r] = f2bf(acc[im][in][r] + bias[m + r]);
          *(uint2*)(Cq + (size_t)n * ldc + m) = *(const uint2*)o;
        } else {
          short* Cv = (short*)C2p + sC2 * bz;
#pragma unroll
          for (int r = 0; r < 4; ++r)
            Cv[(size_t)(m - 1024 + r) * ldc + n] =
                f2bf(acc[im][in][r] + bias[m + r]);
        }
      } else if (EPI == 1) {
        float* Cf = (float*)Cp + sC * bz;
#pragma unroll
        for (int r = 0; r < 4; ++r)
          Cf[(size_t)(m + r) * ldc + n] = acc[im][in][r] * alpha;
      } else if (EPI == 2) {
        short* Cs = (short*)Cp + sC * bz;
#pragma unroll
        for (int r = 0; r < 4; ++r)
          Cs[(size_t)(m + r) * ldc + n] = f2bf(acc[im][in][r]);
      } else {
        float* Cf = (float*)Cp + sC * bz;
        const float* R = resid + sR * bz;
#pragma unroll
        for (int r = 0; r < 4; ++r)
          Cf[(size_t)(m + r) * ldc + n] =
              acc[im][in][r] + bias[m + r] + R[(size_t)(m + r) * ldc + n];
      }
    }
  }
}

// ---------------- row softmax over 1024, fp32 in -> bf16 out ----------------
__global__ __launch_bounds__(256) void softmax_kernel(const float* __restrict__ S,
                                                      short* __restrict__ P) {
  __shared__ float sm[8];
  const float* p = S + (size_t)blockIdx.x * 1024;
  const int t = threadIdx.x;
  float4 v = ((const float4*)p)[t];
  float mx = fmaxf(fmaxf(v.x, v.y), fmaxf(v.z, v.w));
  mx = wave_reduce_max(mx);
  if ((t & 63) == 0) sm[t >> 6] = mx;
  __syncthreads();
  mx = fmaxf(fmaxf(sm[0], sm[1]), fmaxf(sm[2], sm[3]));
  v.x = __expf(v.x - mx);
  v.y = __expf(v.y - mx);
  v.z = __expf(v.z - mx);
  v.w = __expf(v.w - mx);
  float s = v.x + v.y + v.z + v.w;
  s = wave_reduce_sum(s);
  if ((t & 63) == 0) sm[4 + (t >> 6)] = s;
  __syncthreads();
  const float inv = 1.0f / (sm[4] + sm[5] + sm[6] + sm[7]);
  short o[4] = {f2bf(v.x * inv), f2bf(v.y * inv), f2bf(v.z * inv),
                f2bf(v.w * inv)};
  *(uint2*)(P + (size_t)blockIdx.x * 1024 + t * 4) = *(const uint2*)o;
}

// ---------------- launch ----------------
extern "C" void kernel_launch(void* const* d_in, const int* in_sizes, int n_in,
                              void* d_out, int out_size, void* d_ws,
                              size_t ws_size, hipStream_t stream) {
  const float* x = (const float*)d_in[0];
  const float* gnw = (const float*)d_in[1];
  const float* gnb = (const float*)d_in[2];
  const float* qkvw = (const float*)d_in[3];   // [1536, 512]
  const float* qkvb = (const float*)d_in[4];   // [1536]
  const float* projw = (const float*)d_in[5];  // [512, 512]
  const float* projb = (const float*)d_in[6];  // [512]
  float* out = (float*)d_out;

  char* ws = (char*)d_ws;
  short* xnt = (short*)ws;                       //  8 MiB [b][1024 pix][512 c] bf16
  short* qkt = (short*)(ws + (8ull << 20));      // 16 MiB [b][1024 pix][1024: Q|K] bf16
  short* vbuf = (short*)(ws + (24ull << 20));    //  8 MiB [b][512 c][1024 pix] bf16
  float* Sbuf = (float*)(ws + (32ull << 20));    // 32 MiB [b][1024][1024] fp32
  short* Pbuf = (short*)(ws + (64ull << 20));    // 16 MiB [b][1024][1024] bf16
  short* Ot = (short*)(ws + (80ull << 20));      //  8 MiB [b][1024 pix][512 c] bf16
  short* wq = (short*)(ws + (88ull << 20));      // 1.5 MiB
  short* wp = (short*)(ws + (89ull << 20) + (512ull << 10));  // 0.5 MiB

  // weights -> bf16
  cvt_kernel<<<768, 256, 0, stream>>>(qkvw, wq, 1536 * 512);
  cvt_kernel<<<256, 256, 0, stream>>>(projw, wp, 512 * 512);

  // GroupNorm -> xnt (transposed bf16)
  gn_kernel<<<Bsz * NG, 256, 0, stream>>>(x, gnw, gnb, xnt);

  // QKV: C[m][n] = sum_k wq[m][k] xnt[n][k]; M=1536 N=1024 K=512
  //   m<1024 -> qkt[n][m]; m>=1024 -> v[m-1024][n]
  mfma_gemm<0><<<dim3(8, 12, Bsz), 256, 0, stream>>>(
      wq, xnt, 512, 512, 512, 0L, 1024L * 512, qkvb, 1.0f, qkt, 1024L * 1024,
      1024, vbuf, 512L * 1024, nullptr, 0L);

  // S[i][j] = scale * sum_k Q[i][k] K[j][k]; M=N=1024 K=512
  const float scale = 1.0f / sqrtf(512.0f);
  mfma_gemm<1><<<dim3(8, 8, Bsz), 256, 0, stream>>>(
      qkt, qkt + 512, 512, 1024, 1024, 1024L * 1024, 1024L * 1024, nullptr,
      scale, Sbuf, 1024L * 1024, 1024, nullptr, 0L, nullptr, 0L);

  // softmax rows -> P bf16
  softmax_kernel<<<Bsz * 1024, 256, 0, stream>>>(Sbuf, Pbuf);

  // Ot[i][c] = sum_j P[i][j] V[c][j]; M=1024 N=512 K=1024
  mfma_gemm<2><<<dim3(4, 8, Bsz), 256, 0, stream>>>(
      Pbuf, vbuf, 1024, 1024, 1024, 1024L * 1024, 512L * 1024, nullptr, 1.0f,
      Ot, 1024L * 512, 512, nullptr, 0L, nullptr, 0L);

  // out[o][i] = sum_c wp[o][c] Ot[i][c] + projb[o] + x[o][i]; M=512 N=1024 K=512
  mfma_gemm<3><<<dim3(8, 4, Bsz), 256, 0, stream>>>(
      wp, Ot, 512, 512, 512, 0L, 1024L * 512, projb, 1.0f, out, 512L * 1024,
      1024, nullptr, 0L, x, 512L * 1024);
}

// Round 3
// 202.325 us; speedup vs baseline: 3.8965x; 1.0644x over previous
//
#include <hip/hip_runtime.h>
#include <cmath>

// Problem: x [8, 512, 32, 32] fp32. GroupNorm(32) -> QKV 1x1 -> attention -> proj 1x1 -> +x
constexpr int Bsz = 8, Cch = 512, NPIX = 1024;
constexpr int NG = 32, CPG = 16;

typedef __attribute__((ext_vector_type(4))) float f32x4;
typedef __attribute__((ext_vector_type(8))) short s16x8;

#define GLOBAL_AS __attribute__((address_space(1)))
#define LDS_AS __attribute__((address_space(3)))

__device__ inline short f2bf(float f) {  // RNE fp32 -> bf16
  union { float f; unsigned u; } c = {f};
  unsigned r = (c.u + 0x7fffu + ((c.u >> 16) & 1u)) >> 16;
  return (short)r;
}

__device__ inline float wave_reduce_sum(float v) {
#pragma unroll
  for (int off = 32; off > 0; off >>= 1) v += __shfl_xor(v, off, 64);
  return v;
}
__device__ inline float wave_reduce_max(float v) {
#pragma unroll
  for (int off = 32; off > 0; off >>= 1) v = fmaxf(v, __shfl_xor(v, off, 64));
  return v;
}

// ---------------- fp32 -> bf16 weight conversion (both weights, one dispatch) ----
__global__ __launch_bounds__(256) void cvt_kernel(const float* __restrict__ in1,
                                                  short* __restrict__ out1, int n1,
                                                  const float* __restrict__ in2,
                                                  short* __restrict__ out2, int n2) {
  const int i = (blockIdx.x * 256 + threadIdx.x) * 4;
  const float* in = in1;
  short* out = out1;
  int j = i;
  if (i >= n1) { in = in2; out = out2; j = i - n1; }
  if (j + 3 < (i >= n1 ? n2 : n1)) {
    float4 v = *(const float4*)(in + j);
    short o[4] = {f2bf(v.x), f2bf(v.y), f2bf(v.z), f2bf(v.w)};
    *(uint2*)(out + j) = *(const uint2*)o;
  }
}

// ---------------- GroupNorm, writes TRANSPOSED bf16 xnt[b][pix][c] ----------------
__global__ __launch_bounds__(256) void gn_kernel(
    const float* __restrict__ x, const float* __restrict__ w,
    const float* __restrict__ bb, short* __restrict__ xnt) {
  __shared__ float sm[8];
  const int bg = blockIdx.x, b = bg >> 5, g = bg & 31;
  const float* xp = x + ((size_t)(b * Cch + g * CPG)) * NPIX;
  float s = 0.f, ss = 0.f;
  for (int i = threadIdx.x * 4; i < CPG * NPIX; i += 1024) {
    float4 v = *(const float4*)(xp + i);
    s += v.x + v.y + v.z + v.w;
    ss += v.x * v.x + v.y * v.y + v.z * v.z + v.w * v.w;
  }
  s = wave_reduce_sum(s);
  ss = wave_reduce_sum(ss);
  const int wv = threadIdx.x >> 6;
  if ((threadIdx.x & 63) == 0) { sm[wv] = s; sm[4 + wv] = ss; }
  __syncthreads();
  const float tsum = sm[0] + sm[1] + sm[2] + sm[3];
  const float tsq = sm[4] + sm[5] + sm[6] + sm[7];
  const float inv_n = 1.0f / (CPG * NPIX);
  const float mean = tsum * inv_n;
  const float rstd = rsqrtf(tsq * inv_n - mean * mean + 1e-5f);
  float wc[CPG], bc[CPG];
#pragma unroll
  for (int c = 0; c < CPG; ++c) {
    wc[c] = w[g * CPG + c] * rstd;
    bc[c] = bb[g * CPG + c] - mean * wc[c];
  }
  for (int p = threadIdx.x; p < NPIX; p += 256) {
    short ov[CPG];
#pragma unroll
    for (int c = 0; c < CPG; ++c)
      ov[c] = f2bf(xp[(size_t)c * NPIX + p] * wc[c] + bc[c]);
    short* op = xnt + ((size_t)(b * NPIX + p)) * Cch + g * CPG;
    *(uint4*)op = *(const uint4*)&ov[0];
    *(uint4*)(op + 8) = *(const uint4*)&ov[8];
  }
}

// ---------------- bf16 MFMA GEMM: C[m][n] = sum_k A[m][k]*B[n][k] ----------------
// Both operands row-major with k contiguous ("TN"). BM x BN tile, BK=32,
// 256 threads = 4 waves in a 2x2 grid; wave tile (BM/2)x(BN/2) =
// (FM x FN) mfma_f32_16x16x32_bf16 tiles. LDS fragment-ordered: staging is
// linear for global_load_lds and ds_read_b128 fragment reads are conflict-free.
// EPI 0: qkv split  -> m<1024: bf16 Cq[n*ldc+m] (+bias); else bf16 C2[(m-1024)*ldc+n] (+bias)
// EPI 1: fp32 C[m*ldc+n] = acc*alpha
// EPI 2: bf16 C[m*ldc+n] = acc
// EPI 3: fp32 C[m*ldc+n] = acc + bias[m] + resid[m*ldc+n]
template <int BM, int BN, int EPI>
__global__ __launch_bounds__(256) void mfma_gemm(
    const short* __restrict__ A, const short* __restrict__ B, int K, int lda,
    int ldb, long sA, long sB, const float* __restrict__ bias, float alpha,
    void* __restrict__ Cp, long sC, int ldc, void* __restrict__ C2p, long sC2,
    const float* __restrict__ resid, long sR) {
  constexpr int FM = BM / 32, FN = BN / 32;   // frag tiles per wave
  constexpr int NA = BM / 64, NB = BN / 64;   // staging iters (256 thr x 16B)
  __shared__ __align__(16) short Asl[BM * 32];  // fragment-ordered
  __shared__ __align__(16) short Bsl[BN * 32];
  const int t = threadIdx.x;
  const int lane = t & 63, wave = t >> 6;
  const int bz = blockIdx.z;
  const int m0 = blockIdx.y * BM, n0 = blockIdx.x * BN;
  A += sA * bz;
  B += sB * bz;

  // staging: chunk s covers row = (s>>6)*16 + (s&15), k-quad q = (s>>4)&3
  const short* ga[NA];
  const short* gb[NB];
  short* la[NA];
  short* lb[NB];
#pragma unroll
  for (int i = 0; i < NA; ++i) {
    const int s = i * 256 + t;
    const int row = ((s >> 6) * 16) + (s & 15);
    const int q = (s >> 4) & 3;
    ga[i] = A + (size_t)(m0 + row) * lda + q * 8;
    la[i] = Asl + s * 8;
  }
#pragma unroll
  for (int i = 0; i < NB; ++i) {
    const int s = i * 256 + t;
    const int row = ((s >> 6) * 16) + (s & 15);
    const int q = (s >> 4) & 3;
    gb[i] = B + (size_t)(n0 + row) * ldb + q * 8;
    lb[i] = Bsl + s * 8;
  }

  f32x4 acc[FM][FN] = {};
  const int wm = wave & 1, wn = wave >> 1;

  for (int k0 = 0; k0 < K; k0 += 32) {
#pragma unroll
    for (int i = 0; i < NA; ++i) {
      __builtin_amdgcn_global_load_lds((const GLOBAL_AS void*)ga[i],
                                       (LDS_AS void*)la[i], 16, 0, 0);
      ga[i] += 32;
    }
#pragma unroll
    for (int i = 0; i < NB; ++i) {
      __builtin_amdgcn_global_load_lds((const GLOBAL_AS void*)gb[i],
                                       (LDS_AS void*)lb[i], 16, 0, 0);
      gb[i] += 32;
    }
    __syncthreads();
    s16x8 af[FM], bf[FN];
#pragma unroll
    for (int i = 0; i < FM; ++i)
      af[i] = *(const s16x8*)(Asl + (wm * FM + i) * 512 + lane * 8);
#pragma unroll
    for (int i = 0; i < FN; ++i)
      bf[i] = *(const s16x8*)(Bsl + (wn * FN + i) * 512 + lane * 8);
#pragma unroll
    for (int im = 0; im < FM; ++im)
#pragma unroll
      for (int in = 0; in < FN; ++in)
        acc[im][in] = __builtin_amdgcn_mfma_f32_16x16x32_bf16(
            af[im], bf[in], acc[im][in], 0, 0, 0);
    __syncthreads();
  }

  // epilogue. C/D frag: row m = quad*4+r, col n = lane&15 (within 16x16 tile)
  const int quad = lane >> 4, nn = lane & 15;
#pragma unroll
  for (int im = 0; im < FM; ++im) {
#pragma unroll
    for (int in = 0; in < FN; ++in) {
      const int m = m0 + (wm * FM + im) * 16 + quad * 4;
      const int n = n0 + (wn * FN + in) * 16 + nn;
      if (EPI == 0) {
        if (m0 < 1024) {
          short* Cq = (short*)Cp + sC * bz;
          short o[4];
#pragma unroll
          for (int r = 0; r < 4; ++r) o[r] = f2bf(acc[im][in][r] + bias[m + r]);
          *(uint2*)(Cq + (size_t)n * ldc + m) = *(const uint2*)o;
        } else {
          short* Cv = (short*)C2p + sC2 * bz;
#pragma unroll
          for (int r = 0; r < 4; ++r)
            Cv[(size_t)(m - 1024 + r) * ldc + n] =
                f2bf(acc[im][in][r] + bias[m + r]);
        }
      } else if (EPI == 1) {
        float* Cf = (float*)Cp + sC * bz;
#pragma unroll
        for (int r = 0; r < 4; ++r)
          Cf[(size_t)(m + r) * ldc + n] = acc[im][in][r] * alpha;
      } else if (EPI == 2) {
        short* Cs = (short*)Cp + sC * bz;
#pragma unroll
        for (int r = 0; r < 4; ++r)
          Cs[(size_t)(m + r) * ldc + n] = f2bf(acc[im][in][r]);
      } else {
        float* Cf = (float*)Cp + sC * bz;
        const float* R = resid + sR * bz;
#pragma unroll
        for (int r = 0; r < 4; ++r)
          Cf[(size_t)(m + r) * ldc + n] =
              acc[im][in][r] + bias[m + r] + R[(size_t)(m + r) * ldc + n];
      }
    }
  }
}

// ---------------- row softmax over 1024, fp32 in -> bf16 out ----------------
__global__ __launch_bounds__(256) void softmax_kernel(const float* __restrict__ S,
                                                      short* __restrict__ P) {
  __shared__ float sm[8];
  const float* p = S + (size_t)blockIdx.x * 1024;
  const int t = threadIdx.x;
  float4 v = ((const float4*)p)[t];
  float mx = fmaxf(fmaxf(v.x, v.y), fmaxf(v.z, v.w));
  mx = wave_reduce_max(mx);
  if ((t & 63) == 0) sm[t >> 6] = mx;
  __syncthreads();
  mx = fmaxf(fmaxf(sm[0], sm[1]), fmaxf(sm[2], sm[3]));
  v.x = __expf(v.x - mx);
  v.y = __expf(v.y - mx);
  v.z = __expf(v.z - mx);
  v.w = __expf(v.w - mx);
  float s = v.x + v.y + v.z + v.w;
  s = wave_reduce_sum(s);
  if ((t & 63) == 0) sm[4 + (t >> 6)] = s;
  __syncthreads();
  const float inv = 1.0f / (sm[4] + sm[5] + sm[6] + sm[7]);
  short o[4] = {f2bf(v.x * inv), f2bf(v.y * inv), f2bf(v.z * inv),
                f2bf(v.w * inv)};
  *(uint2*)(P + (size_t)blockIdx.x * 1024 + t * 4) = *(const uint2*)o;
}

// ---------------- launch ----------------
extern "C" void kernel_launch(void* const* d_in, const int* in_sizes, int n_in,
                              void* d_out, int out_size, void* d_ws,
                              size_t ws_size, hipStream_t stream) {
  const float* x = (const float*)d_in[0];
  const float* gnw = (const float*)d_in[1];
  const float* gnb = (const float*)d_in[2];
  const float* qkvw = (const float*)d_in[3];   // [1536, 512]
  const float* qkvb = (const float*)d_in[4];   // [1536]
  const float* projw = (const float*)d_in[5];  // [512, 512]
  const float* projb = (const float*)d_in[6];  // [512]
  float* out = (float*)d_out;

  char* ws = (char*)d_ws;
  short* xnt = (short*)ws;                       //  8 MiB [b][1024 pix][512 c] bf16
  short* qkt = (short*)(ws + (8ull << 20));      // 16 MiB [b][1024 pix][1024: Q|K] bf16
  short* vbuf = (short*)(ws + (24ull << 20));    //  8 MiB [b][512 c][1024 pix] bf16
  float* Sbuf = (float*)(ws + (32ull << 20));    // 32 MiB [b][1024][1024] fp32
  short* Pbuf = (short*)(ws + (64ull << 20));    // 16 MiB [b][1024][1024] bf16
  short* Ot = (short*)(ws + (80ull << 20));      //  8 MiB [b][1024 pix][512 c] bf16
  short* wq = (short*)(ws + (88ull << 20));      // 1.5 MiB
  short* wp = (short*)(ws + (89ull << 20) + (512ull << 10));  // 0.5 MiB

  // weights -> bf16 (one dispatch covers both)
  cvt_kernel<<<1024, 256, 0, stream>>>(qkvw, wq, 1536 * 512, projw, wp,
                                       512 * 512);

  // GroupNorm -> xnt (transposed bf16)
  gn_kernel<<<Bsz * NG, 256, 0, stream>>>(x, gnw, gnb, xnt);

  // QKV: C[m][n] = sum_k wq[m][k] xnt[n][k]; M=1536 N=1024 K=512
  //   m<1024 -> qkt[n][m]; m>=1024 -> v[m-1024][n]
  mfma_gemm<128, 128, 0><<<dim3(8, 12, Bsz), 256, 0, stream>>>(
      wq, xnt, 512, 512, 512, 0L, 1024L * 512, qkvb, 1.0f, qkt, 1024L * 1024,
      1024, vbuf, 512L * 1024, nullptr, 0L);

  // S[i][j] = scale * sum_k Q[i][k] K[j][k]; M=N=1024 K=512
  const float scale = 1.0f / sqrtf(512.0f);
  mfma_gemm<128, 128, 1><<<dim3(8, 8, Bsz), 256, 0, stream>>>(
      qkt, qkt + 512, 512, 1024, 1024, 1024L * 1024, 1024L * 1024, nullptr,
      scale, Sbuf, 1024L * 1024, 1024, nullptr, 0L, nullptr, 0L);

  // softmax rows -> P bf16
  softmax_kernel<<<Bsz * 1024, 256, 0, stream>>>(Sbuf, Pbuf);

  // Ot[i][c] = sum_j P[i][j] V[c][j]; M=1024 N=512 K=1024  (128x64 -> 512 blocks)
  mfma_gemm<128, 64, 2><<<dim3(8, 8, Bsz), 256, 0, stream>>>(
      Pbuf, vbuf, 1024, 1024, 1024, 1024L * 1024, 512L * 1024, nullptr, 1.0f,
      Ot, 1024L * 512, 512, nullptr, 0L, nullptr, 0L);

  // out[o][i] = sum_c wp[o][c] Ot[i][c] + projb[o] + x[o][i]; M=512 N=1024 K=512
  // (64x128 -> 512 blocks)
  mfma_gemm<64, 128, 3><<<dim3(8, 8, Bsz), 256, 0, stream>>>(
      wp, Ot, 512, 512, 512, 0L, 1024L * 512, projb, 1.0f, out, 512L * 1024,
      1024, nullptr, 0L, x, 512L * 1024);
}